// Round 2
// baseline (7832.857 us; speedup 1.0000x reference)
//
#include <hip/hip_runtime.h>
#include <math.h>

// ---------------------------------------------------------------------------
// QuantMlp: out = fq(h)@fq(W2)^T + b2,  h = gelu(fq(LN(x))@fq(W1)^T + b1)
// fq: per-tensor symmetric int8 fake-quant. q-values are small integers ->
// EXACT in bf16; bf16-MFMA fp32 accumulation of q*q' is exact (sums < 2^24).
//
// R3 -> R4: same 256x256 tile / 8-wave / counted-vmcnt phase pipeline, but
// LDS cut 128KB -> 80KB (BK=32; A 2-buffered, B 3-buffered, 5 x 16KB regions;
// 'red' aliased into LDS post-loop) so TWO blocks fit per CU (2x80KB=160KB
// exactly, 512B granule). With K small (12/48 BK=64-tiles) and a fat erf
// epilogue, 1 block/CU serialized prologue fill + drain + epilogue per block;
// a second resident block overlaps all three (m114 mechanism).
// Per-block MFMA/ds_read/gll16/barrier counts are unchanged vs R3.
// ---------------------------------------------------------------------------

typedef __attribute__((ext_vector_type(4))) float  f4;
typedef __attribute__((ext_vector_type(8))) __bf16 bf16x8;
typedef __attribute__((ext_vector_type(4))) unsigned short us4;
typedef __attribute__((ext_vector_type(4))) unsigned int   u4;

__device__ __forceinline__ unsigned short f2bf_rn(float f) {
    unsigned u = __float_as_uint(f);
    u += 0x7FFFu + ((u >> 16) & 1u);          // round-to-nearest-even
    return (unsigned short)(u >> 16);
}
__device__ __forceinline__ float bf2f(unsigned short b) {
    return __uint_as_float(((unsigned)b) << 16);
}

// all-threads block -> single device atomicMax of a non-negative float
template <int NW>
__device__ __forceinline__ void block_atomic_max(float v, unsigned* slot,
                                                 float* red, int tid) {
    int lane = tid & 63, wv = tid >> 6;
    #pragma unroll
    for (int m = 32; m; m >>= 1) v = fmaxf(v, __shfl_xor(v, m));
    if (lane == 0) red[wv] = v;
    __syncthreads();
    if (tid == 0) {
        float r = red[0];
        #pragma unroll
        for (int i = 1; i < NW; i++) r = fmaxf(r, red[i]);
        atomicMax(slot, __float_as_uint(r));
    }
}

// async 16B global->LDS (wave-uniform base + lane*16 by construction)
__device__ __forceinline__ void gll16(const void* g, void* l) {
    __builtin_amdgcn_global_load_lds(
        (const __attribute__((address_space(1))) void*)g,
        (__attribute__((address_space(3))) void*)l, 16, 0, 0);
}

// ---------------------------------------------------------------------------
// LayerNorm helpers: one wave per row of 768 (12 floats/lane as 3x float4)
// ---------------------------------------------------------------------------
__device__ __forceinline__ void ln_row(const f4* xr, int lane, f4 v[3],
                                       float& mu, float& rs) {
    float s = 0.f;
    #pragma unroll
    for (int c = 0; c < 3; c++) {
        v[c] = xr[lane + 64 * c];
        s += v[c][0] + v[c][1] + v[c][2] + v[c][3];
    }
    #pragma unroll
    for (int m = 1; m < 64; m <<= 1) s += __shfl_xor(s, m);
    mu = s * (1.0f / 768.0f);
    float q = 0.f;
    #pragma unroll
    for (int c = 0; c < 3; c++) {
        #pragma unroll
        for (int k = 0; k < 4; k++) { float d = v[c][k] - mu; q += d * d; }
    }
    #pragma unroll
    for (int m = 1; m < 64; m <<= 1) q += __shfl_xor(q, m);
    rs = rsqrtf(q * (1.0f / 768.0f) + 1e-5f);
}

__global__ __launch_bounds__(256) void ln_absmax_kernel(
        const float* __restrict__ x, const float* __restrict__ gamma,
        const float* __restrict__ beta, unsigned* __restrict__ slot, long NR) {
    __shared__ float red[4];
    int tid = threadIdx.x, lane = tid & 63, wv = tid >> 6;
    const f4* g4 = (const f4*)gamma;
    const f4* b4 = (const f4*)beta;
    long rstep = (long)gridDim.x * 4;
    float wmax = 0.f;
    for (long row = (long)blockIdx.x * 4 + wv; row < NR; row += rstep) {
        const f4* xr = (const f4*)(x + row * 768);
        f4 v[3]; float mu, rs;
        ln_row(xr, lane, v, mu, rs);
        #pragma unroll
        for (int c = 0; c < 3; c++) {
            f4 g = g4[lane + 64 * c], b = b4[lane + 64 * c];
            #pragma unroll
            for (int k = 0; k < 4; k++) {
                float xn = (v[c][k] - mu) * rs * g[k] + b[k];
                wmax = fmaxf(wmax, fabsf(xn));
            }
        }
    }
    block_atomic_max<4>(wmax, slot, red, tid);
}

__global__ __launch_bounds__(256) void ln_quant_kernel(
        const float* __restrict__ x, const float* __restrict__ gamma,
        const float* __restrict__ beta, unsigned short* __restrict__ qx,
        const unsigned* __restrict__ amax_bits, long NR) {
    int tid = threadIdx.x, lane = tid & 63, wv = tid >> 6;
    long row = (long)blockIdx.x * 4 + wv;
    if (row >= NR) return;
    float sx = fmaxf(__uint_as_float(*amax_bits) * (1.0f / 128.0f), 1e-12f);
    const f4* xr = (const f4*)(x + row * 768);
    const f4* g4 = (const f4*)gamma;
    const f4* b4 = (const f4*)beta;
    f4 v[3]; float mu, rs;
    ln_row(xr, lane, v, mu, rs);
    us4* qr = (us4*)(qx + row * 768);
    #pragma unroll
    for (int c = 0; c < 3; c++) {
        f4 g = g4[lane + 64 * c], b = b4[lane + 64 * c];
        us4 o;
        #pragma unroll
        for (int k = 0; k < 4; k++) {
            float xn = (v[c][k] - mu) * rs * g[k] + b[k];
            float q = fminf(fmaxf(rintf(xn / sx), -128.0f), 127.0f);
            o[k] = f2bf_rn(q);   // exact: small integer
        }
        qr[lane + 64 * c] = o;
    }
}

// ---------------------------------------------------------------------------
// Weight absmax + quantize (fp32 -> integer-valued bf16)
// ---------------------------------------------------------------------------
__global__ __launch_bounds__(256) void absmax_kernel(
        const float* __restrict__ w, long n4, unsigned* __restrict__ slot) {
    __shared__ float red[4];
    int tid = threadIdx.x;
    long stride = (long)gridDim.x * 256;
    float mx = 0.f;
    for (long i = (long)blockIdx.x * 256 + tid; i < n4; i += stride) {
        f4 v = ((const f4*)w)[i];
        mx = fmaxf(mx, fmaxf(fmaxf(fabsf(v[0]), fabsf(v[1])),
                             fmaxf(fabsf(v[2]), fabsf(v[3]))));
    }
    block_atomic_max<4>(mx, slot, red, tid);
}

__global__ __launch_bounds__(256) void quant_w_kernel(
        const float* __restrict__ w, unsigned short* __restrict__ qw, long n4,
        const unsigned* __restrict__ amax_bits) {
    long i = (long)blockIdx.x * 256 + threadIdx.x;
    if (i >= n4) return;
    float s = fmaxf(__uint_as_float(*amax_bits) * (1.0f / 127.0f), 1e-12f);
    f4 v = ((const f4*)w)[i];
    us4 o;
    #pragma unroll
    for (int k = 0; k < 4; k++) {
        float q = fminf(fmaxf(rintf(v[k] / s), -127.0f), 127.0f);
        o[k] = f2bf_rn(q);
    }
    ((us4*)qw)[i] = o;
}

// h (bf16) -> q (integer-valued bf16), in place. 8 elements / thread.
__global__ __launch_bounds__(256) void quant_h_kernel(
        unsigned short* __restrict__ h, const unsigned* __restrict__ amax_bits,
        long n8) {
    long i = (long)blockIdx.x * 256 + threadIdx.x;
    if (i >= n8) return;
    float s = fmaxf(__uint_as_float(*amax_bits) * (1.0f / 128.0f), 1e-12f);
    u4 d = ((const u4*)h)[i];
    u4 o;
    #pragma unroll
    for (int k = 0; k < 4; k++) {
        float a = bf2f((unsigned short)(d[k] & 0xFFFFu));
        float b = bf2f((unsigned short)(d[k] >> 16));
        float qa = fminf(fmaxf(rintf(a / s), -128.0f), 127.0f);
        float qb = fminf(fmaxf(rintf(b / s), -128.0f), 127.0f);
        o[k] = (unsigned)f2bf_rn(qa) | ((unsigned)f2bf_rn(qb) << 16);
    }
    ((u4*)h)[i] = o;
}

// ---------------------------------------------------------------------------
// GEMM: C[M,N] = A[M,K] * B[N,K]^T, A/B integer-valued bf16, K-contiguous.
// 256x256 tile, BK=32, 512 threads = 8 waves (2M x 4N), per-wave 128x64 out.
// LDS 80KB = A buffers {A0,A1} + B buffers {B0,B1,B2}, each 16KB:
//   region = 256 rows x 4 chunks of 16B; chunk swizzle c' = c^((r>>1)&3)
//   (pre-swizzled GLOBAL source, linear LDS dest, swizzled ds_read; measured
//    SQ_LDS_BANK_CONFLICT == 0 with this layout in R3).
// Tile t: A in A[t&1], B in B[t%3]. Per tile 2 phases (MB=0 w/ bF, MB=4):
//   {ds_read frags | stage 2 gll16 | barrier | lgkm(0) | prio1 16-MFMA prio0
//    | [VMC(2) at P1] | barrier}
// Stage schedule: u.P0 stages A(u+1) (overwrites A(u-1), last read u-1.P1,
// 1 barrier prior); u.P1 stages B(u+2) (overwrites B(u-1), last read u-1.P0,
// 3 barriers prior). vmcnt(2) per tile leaves exactly B(u+2) in flight;
// A has ~2-phase latency cover, B ~3-phase. 6-tile unrolled loop (A period 2,
// B period 3); requires K % 192 == 0 (768, 3072 both OK).
// ---------------------------------------------------------------------------
#define RA0 0
#define RA1 16384
#define RB0 32768
#define RB1 49152
#define RB2 65536
#define SA(eo, rb) { gll16(gA[0]+(eo), lds+(rb)+ldst[0]); \
                     gll16(gA[1]+(eo), lds+(rb)+ldst[1]); }
#define SB(eo, rb) { gll16(gB[0]+(eo), lds+(rb)+ldst[0]); \
                     gll16(gB[1]+(eo), lds+(rb)+ldst[1]); }
#define VMC(n) asm volatile("s_waitcnt vmcnt(" #n ")" ::: "memory")

#define PH(AR, BR, MB, STAGE, TAIL) do {                                      \
    bf16x8 aF[4];                                                             \
    _Pragma("unroll")                                                         \
    for (int m_ = 0; m_ < 4; m_++)                                            \
      aF[m_] = *(const bf16x8*)(lds + (AR) + aoff + (MB + m_) * 1024);        \
    if (MB == 0) {                                                            \
      _Pragma("unroll")                                                       \
      for (int n_ = 0; n_ < 4; n_++)                                          \
        bF[n_] = *(const bf16x8*)(lds + (BR) + boff + n_ * 1024);             \
    }                                                                         \
    STAGE                                                                     \
    __builtin_amdgcn_s_barrier();                                             \
    asm volatile("s_waitcnt lgkmcnt(0)" ::: "memory");                        \
    __builtin_amdgcn_s_setprio(1);                                            \
    _Pragma("unroll")                                                         \
    for (int m_ = 0; m_ < 4; m_++)                                            \
      _Pragma("unroll")                                                       \
      for (int n_ = 0; n_ < 4; n_++)                                          \
        acc[MB + m_][n_] = __builtin_amdgcn_mfma_f32_16x16x32_bf16(           \
            aF[m_], bF[n_], acc[MB + m_][n_], 0, 0, 0);                       \
    __builtin_amdgcn_s_setprio(0);                                            \
    TAIL                                                                      \
    __builtin_amdgcn_s_barrier();                                             \
  } while (0)

template <int EPI>
__global__ __launch_bounds__(512, 4) void gemm256(
        const unsigned short* __restrict__ A, const unsigned short* __restrict__ B,
        int K, const unsigned* __restrict__ amaxA_bits,
        const unsigned* __restrict__ amaxB_bits, const float* __restrict__ bias,
        void* __restrict__ Cout, int ldc, unsigned* __restrict__ amax_out) {
    // exactly 80 KB (512B-granule exact) -> 2 blocks/CU. red aliased in.
    __shared__ __align__(16) char lds[81920];
    float* red = (float*)lds;   // used only after the final phase barrier
    int tid = threadIdx.x, lane = tid & 63, wv = tid >> 6;
    int wm = wv >> 2, wn = wv & 3;

    // T1: XCD-contiguous block remap (nwg % 8 == 0 for both launches)
    int nwg = gridDim.x * gridDim.y;
    int flat = blockIdx.y * gridDim.x + blockIdx.x;
    int swz = (flat & 7) * (nwg >> 3) + (flat >> 3);
    int ncol = gridDim.x;
    long rowBase = (long)(swz / ncol) * 256;
    long colBase = (long)(swz % ncol) * 256;

    f4 acc[8][4] = {};
    bf16x8 bF[4];

    // read-side offsets: frag row rl = lane&15, k-chunk cq = lane>>4,
    // swizzled chunk = cq ^ ((rl>>1)&3). Region row stride 64B.
    int rl = lane & 15, cq = lane >> 4;
    int roff = rl * 64 + ((cq ^ ((rl >> 1) & 3)) * 16);
    int aoff = wm * 8192 + roff;            // + m*1024 + region base
    int boff = wn * 4096 + roff;            // + n*1024 + region base

    // stage-side: slot s = p*512+tid -> row r = s>>2, global chunk
    // gc = (s&3) ^ ((r>>1)&3) (inverse of read swizzle); LDS dest linear.
    const unsigned short* gA[2]; const unsigned short* gB[2]; int ldst[2];
    #pragma unroll
    for (int p = 0; p < 2; p++) {
        int s = p * 512 + tid;
        int r = s >> 2;
        int gc = (s & 3) ^ ((r >> 1) & 3);
        gA[p] = A + (rowBase + r) * (long)K + gc * 8;
        gB[p] = B + (colBase + r) * (long)K + gc * 8;
        ldst[p] = s * 16;
    }

    // prologue: A(0), B(0), B(1); vmcnt(2) leaves B(1) in flight (matches
    // steady-state invariant at tile-0 entry: leftover == B(u+1)).
    SA(0, RA0);
    SB(0, RB0);
    SB(32, RB1);
    VMC(2);
    __builtin_amdgcn_s_barrier();

    // main loop: 6 tiles / iter; full-stage iters cover tiles 0..NT-7
    const int nit = K / 192 - 1;
    for (int i = 0; i < nit; i++) {
        PH(RA0, RB0, 0, { SA(32, RA1);  },          );   // t0.P0
        PH(RA0, RB0, 4, { SB(64, RB2);  }, VMC(2);  );   // t0.P1
        PH(RA1, RB1, 0, { SA(64, RA0);  },          );   // t1.P0
        PH(RA1, RB1, 4, { SB(96, RB0);  }, VMC(2);  );   // t1.P1
        PH(RA0, RB2, 0, { SA(96, RA1);  },          );   // t2.P0
        PH(RA0, RB2, 4, { SB(128, RB1); }, VMC(2);  );   // t2.P1
        PH(RA1, RB0, 0, { SA(128, RA0); },          );   // t3.P0
        PH(RA1, RB0, 4, { SB(160, RB2); }, VMC(2);  );   // t3.P1
        PH(RA0, RB1, 0, { SA(160, RA1); },          );   // t4.P0
        PH(RA0, RB1, 4, { SB(192, RB0); }, VMC(2);  );   // t4.P1
        PH(RA1, RB2, 0, { SA(192, RA0); },          );   // t5.P0
        PH(RA1, RB2, 4, { SB(224, RB1); }, VMC(2);  );   // t5.P1
        gA[0] += 192; gA[1] += 192; gB[0] += 192; gB[1] += 192;
    }
    // tail: last 6 tiles; stop staging past NT-1, drain at t4.P1.
    PH(RA0, RB0, 0, { SA(32, RA1);  },          );
    PH(RA0, RB0, 4, { SB(64, RB2);  }, VMC(2);  );
    PH(RA1, RB1, 0, { SA(64, RA0);  },          );
    PH(RA1, RB1, 4, { SB(96, RB0);  }, VMC(2);  );
    PH(RA0, RB2, 0, { SA(96, RA1);  },          );
    PH(RA0, RB2, 4, { SB(128, RB1); }, VMC(2);  );
    PH(RA1, RB0, 0, { SA(128, RA0); },          );
    PH(RA1, RB0, 4, { SB(160, RB2); }, VMC(2);  );
    PH(RA0, RB1, 0, { SA(160, RA1); },          );
    PH(RA0, RB1, 4, { },               VMC(0);  );
    PH(RA1, RB2, 0, { },                        );
    PH(RA1, RB2, 4, { },                        );

    float sA = fmaxf(__uint_as_float(*amaxA_bits) * (1.0f / 128.0f), 1e-12f);
    float sB = fmaxf(__uint_as_float(*amaxB_bits) * (1.0f / 127.0f), 1e-12f);
    float sAB = sA * sB;
    int cr = cq * 4;            // C row base within 16 (row=(lane>>4)*4+reg)
    int cc = rl;                // C col within 16     (col=lane&15)

    if (EPI == 0) {
        unsigned short* Hm = (unsigned short*)Cout;
        float mx = 0.f;
        #pragma unroll
        for (int n = 0; n < 4; n++) {
            long col = colBase + wn * 64 + n * 16 + cc;
            float bv = bias[col];
            #pragma unroll
            for (int m = 0; m < 8; m++) {
                long row0 = rowBase + wm * 128 + m * 16 + cr;
                #pragma unroll
                for (int r = 0; r < 4; r++) {
                    float v = acc[m][n][r] * sAB + bv;
                    float g = 0.5f * v * (1.0f + erff(v * 0.70710678118654752f));
                    mx = fmaxf(mx, fabsf(g));
                    Hm[(row0 + r) * (long)ldc + col] = f2bf_rn(g);
                }
            }
        }
        block_atomic_max<8>(mx, amax_out, red, tid);
    } else {
        float* O = (float*)Cout;
        #pragma unroll
        for (int n = 0; n < 4; n++) {
            long col = colBase + wn * 64 + n * 16 + cc;
            float bv = bias[col];
            #pragma unroll
            for (int m = 0; m < 8; m++) {
                long row0 = rowBase + wm * 128 + m * 16 + cr;
                #pragma unroll
                for (int r = 0; r < 4; r++)
                    O[(row0 + r) * (long)ldc + col] = acc[m][n][r] * sAB + bv;
            }
        }
    }
}

// ---------------------------------------------------------------------------
extern "C" void kernel_launch(void* const* d_in, const int* in_sizes, int n_in,
                              void* d_out, int out_size, void* d_ws, size_t ws_size,
                              hipStream_t stream) {
    const float* x     = (const float*)d_in[0];
    const float* gamma = (const float*)d_in[1];
    const float* beta  = (const float*)d_in[2];
    const float* W1    = (const float*)d_in[3];
    const float* b1    = (const float*)d_in[4];
    const float* W2    = (const float*)d_in[5];
    const float* b2    = (const float*)d_in[6];
    float* out = (float*)d_out;

    const int  D  = in_sizes[1];          // 768
    const int  H  = in_sizes[4];          // 3072
    const long NR = (long)in_sizes[0] / D;  // 65536

    char* ws = (char*)d_ws;
    unsigned* amax = (unsigned*)ws;                 // [0]=x [1]=W1 [2]=W2 [3]=h
    unsigned short* qx  = (unsigned short*)(ws + 256);
    unsigned short* qw1 = qx  + (size_t)NR * D;
    unsigned short* qw2 = qw1 + (size_t)H * D;
    unsigned short* hq  = qw2 + (size_t)H * D;      // NR*H bf16

    hipMemsetAsync(amax, 0, 16, stream);

    long wn4 = (long)H * D / 4;
    absmax_kernel<<<1024, 256, 0, stream>>>(W1, wn4, amax + 1);
    absmax_kernel<<<1024, 256, 0, stream>>>(W2, wn4, amax + 2);
    ln_absmax_kernel<<<2048, 256, 0, stream>>>(x, gamma, beta, amax + 0, NR);

    quant_w_kernel<<<(unsigned)((wn4 + 255) / 256), 256, 0, stream>>>(W1, qw1, wn4, amax + 1);
    quant_w_kernel<<<(unsigned)((wn4 + 255) / 256), 256, 0, stream>>>(W2, qw2, wn4, amax + 2);
    ln_quant_kernel<<<(unsigned)(NR / 4), 256, 0, stream>>>(x, gamma, beta, qx, amax + 0, NR);

    dim3 g1(H / 256, (unsigned)(NR / 256));   // 12 x 256 = 3072 wg (%8==0)
    gemm256<0><<<g1, 512, 0, stream>>>(qx, qw1, D, amax + 0, amax + 1, b1,
                                       (void*)hq, H, amax + 3);

    long n8 = NR * (long)H / 8;
    quant_h_kernel<<<(unsigned)((n8 + 255) / 256), 256, 0, stream>>>(hq, amax + 3, n8);

    dim3 g2(D / 256, (unsigned)(NR / 256));   // 3 x 256 = 768 wg (%8==0)
    gemm256<1><<<g2, 512, 0, stream>>>(hq, qw2, H, amax + 3, amax + 2, b2,
                                       (void*)out, D, nullptr);
}

// Round 3
// 1612.292 us; speedup vs baseline: 4.8582x; 4.8582x over previous
//
#include <hip/hip_runtime.h>
#include <math.h>

// ---------------------------------------------------------------------------
// QuantMlp: out = fq(h)@fq(W2)^T + b2,  h = gelu(fq(LN(x))@fq(W1)^T + b1)
// fq: per-tensor symmetric int8 fake-quant. q-values are small integers ->
// EXACT in bf16; bf16-MFMA fp32 accumulation of q*q' is exact (sums < 2^24).
//
// R4 -> R5: R4's launch_bounds(512,4) capped regs at 128 -> accumulator
// spilled to scratch (VGPR=64, FETCH 6.6GB, 4ms). 2 blocks/CU at 256^2 tile
// is register-impossible; revert to R1's proven pipeline (604us/gemm) and:
//  (a) epilogue reordered n-innermost: each output row's 128B window written
//      back-to-back (R1 write amplification: 812MB written for 402MB data).
//  (b) quant_h (804MB streaming RMW pass) ELIMINATED: gemm2 (gemm256q)
//      quantizes its A-tiles on the fly during staging (reg-load via inline
//      asm global_load_dwordx4 at P0, vmcnt-wait + quantize + ds_write at P2;
//      B keeps gll16; waits vmcnt(6)@P1 / vmcnt(2)@P2-stage / vmcnt(2)@P3,
//      all region overwrites >=1 barrier after last read).
// ---------------------------------------------------------------------------

typedef __attribute__((ext_vector_type(4))) float  f4;
typedef __attribute__((ext_vector_type(8))) __bf16 bf16x8;
typedef __attribute__((ext_vector_type(4))) unsigned short us4;
typedef __attribute__((ext_vector_type(4))) unsigned int   u4;

__device__ __forceinline__ unsigned short f2bf_rn(float f) {
    unsigned u = __float_as_uint(f);
    u += 0x7FFFu + ((u >> 16) & 1u);          // round-to-nearest-even
    return (unsigned short)(u >> 16);
}
__device__ __forceinline__ float bf2f(unsigned short b) {
    return __uint_as_float(((unsigned)b) << 16);
}

// all-threads block -> single device atomicMax of a non-negative float
template <int NW>
__device__ __forceinline__ void block_atomic_max(float v, unsigned* slot,
                                                 float* red, int tid) {
    int lane = tid & 63, wv = tid >> 6;
    #pragma unroll
    for (int m = 32; m; m >>= 1) v = fmaxf(v, __shfl_xor(v, m));
    if (lane == 0) red[wv] = v;
    __syncthreads();
    if (tid == 0) {
        float r = red[0];
        #pragma unroll
        for (int i = 1; i < NW; i++) r = fmaxf(r, red[i]);
        atomicMax(slot, __float_as_uint(r));
    }
}

// async 16B global->LDS (wave-uniform base + lane*16 by construction)
__device__ __forceinline__ void gll16(const void* g, void* l) {
    __builtin_amdgcn_global_load_lds(
        (const __attribute__((address_space(1))) void*)g,
        (__attribute__((address_space(3))) void*)l, 16, 0, 0);
}

// pinned-order 16B global->VGPR load (no auto-waitcnt: caller must VMC
// before USING the result; asm volatile keeps issue order vs gll16).
__device__ __forceinline__ u4 gld16(const void* p) {
    u4 r;
    asm volatile("global_load_dwordx4 %0, %1, off"
                 : "=v"(r) : "v"(p) : "memory");
    return r;
}

// quantize 8 packed bf16 (one u4) -> integer-valued bf16, act range.
// Same ops as the removed quant_h kernel (mul-by-reciprocal; rint; clamp).
__device__ __forceinline__ u4 quant8(u4 d, float inv_s) {
    u4 o;
    #pragma unroll
    for (int k = 0; k < 4; k++) {
        float lo = __uint_as_float(d[k] << 16);
        float hi = __uint_as_float(d[k] & 0xFFFF0000u);
        float qa = fminf(fmaxf(rintf(lo * inv_s), -128.0f), 127.0f);
        float qb = fminf(fmaxf(rintf(hi * inv_s), -128.0f), 127.0f);
        o[k] = (unsigned)f2bf_rn(qa) | ((unsigned)f2bf_rn(qb) << 16);
    }
    return o;
}

// ---------------------------------------------------------------------------
// LayerNorm helpers: one wave per row of 768 (12 floats/lane as 3x float4)
// ---------------------------------------------------------------------------
__device__ __forceinline__ void ln_row(const f4* xr, int lane, f4 v[3],
                                       float& mu, float& rs) {
    float s = 0.f;
    #pragma unroll
    for (int c = 0; c < 3; c++) {
        v[c] = xr[lane + 64 * c];
        s += v[c][0] + v[c][1] + v[c][2] + v[c][3];
    }
    #pragma unroll
    for (int m = 1; m < 64; m <<= 1) s += __shfl_xor(s, m);
    mu = s * (1.0f / 768.0f);
    float q = 0.f;
    #pragma unroll
    for (int c = 0; c < 3; c++) {
        #pragma unroll
        for (int k = 0; k < 4; k++) { float d = v[c][k] - mu; q += d * d; }
    }
    #pragma unroll
    for (int m = 1; m < 64; m <<= 1) q += __shfl_xor(q, m);
    rs = rsqrtf(q * (1.0f / 768.0f) + 1e-5f);
}

__global__ __launch_bounds__(256) void ln_absmax_kernel(
        const float* __restrict__ x, const float* __restrict__ gamma,
        const float* __restrict__ beta, unsigned* __restrict__ slot, long NR) {
    __shared__ float red[4];
    int tid = threadIdx.x, lane = tid & 63, wv = tid >> 6;
    const f4* g4 = (const f4*)gamma;
    const f4* b4 = (const f4*)beta;
    long rstep = (long)gridDim.x * 4;
    float wmax = 0.f;
    for (long row = (long)blockIdx.x * 4 + wv; row < NR; row += rstep) {
        const f4* xr = (const f4*)(x + row * 768);
        f4 v[3]; float mu, rs;
        ln_row(xr, lane, v, mu, rs);
        #pragma unroll
        for (int c = 0; c < 3; c++) {
            f4 g = g4[lane + 64 * c], b = b4[lane + 64 * c];
            #pragma unroll
            for (int k = 0; k < 4; k++) {
                float xn = (v[c][k] - mu) * rs * g[k] + b[k];
                wmax = fmaxf(wmax, fabsf(xn));
            }
        }
    }
    block_atomic_max<4>(wmax, slot, red, tid);
}

__global__ __launch_bounds__(256) void ln_quant_kernel(
        const float* __restrict__ x, const float* __restrict__ gamma,
        const float* __restrict__ beta, unsigned short* __restrict__ qx,
        const unsigned* __restrict__ amax_bits, long NR) {
    int tid = threadIdx.x, lane = tid & 63, wv = tid >> 6;
    long row = (long)blockIdx.x * 4 + wv;
    if (row >= NR) return;
    float sx = fmaxf(__uint_as_float(*amax_bits) * (1.0f / 128.0f), 1e-12f);
    const f4* xr = (const f4*)(x + row * 768);
    const f4* g4 = (const f4*)gamma;
    const f4* b4 = (const f4*)beta;
    f4 v[3]; float mu, rs;
    ln_row(xr, lane, v, mu, rs);
    us4* qr = (us4*)(qx + row * 768);
    #pragma unroll
    for (int c = 0; c < 3; c++) {
        f4 g = g4[lane + 64 * c], b = b4[lane + 64 * c];
        us4 o;
        #pragma unroll
        for (int k = 0; k < 4; k++) {
            float xn = (v[c][k] - mu) * rs * g[k] + b[k];
            float q = fminf(fmaxf(rintf(xn / sx), -128.0f), 127.0f);
            o[k] = f2bf_rn(q);   // exact: small integer
        }
        qr[lane + 64 * c] = o;
    }
}

// ---------------------------------------------------------------------------
// Weight absmax + quantize (fp32 -> integer-valued bf16)
// ---------------------------------------------------------------------------
__global__ __launch_bounds__(256) void absmax_kernel(
        const float* __restrict__ w, long n4, unsigned* __restrict__ slot) {
    __shared__ float red[4];
    int tid = threadIdx.x;
    long stride = (long)gridDim.x * 256;
    float mx = 0.f;
    for (long i = (long)blockIdx.x * 256 + tid; i < n4; i += stride) {
        f4 v = ((const f4*)w)[i];
        mx = fmaxf(mx, fmaxf(fmaxf(fabsf(v[0]), fabsf(v[1])),
                             fmaxf(fabsf(v[2]), fabsf(v[3]))));
    }
    block_atomic_max<4>(mx, slot, red, tid);
}

__global__ __launch_bounds__(256) void quant_w_kernel(
        const float* __restrict__ w, unsigned short* __restrict__ qw, long n4,
        const unsigned* __restrict__ amax_bits) {
    long i = (long)blockIdx.x * 256 + threadIdx.x;
    if (i >= n4) return;
    float s = fmaxf(__uint_as_float(*amax_bits) * (1.0f / 127.0f), 1e-12f);
    f4 v = ((const f4*)w)[i];
    us4 o;
    #pragma unroll
    for (int k = 0; k < 4; k++) {
        float q = fminf(fmaxf(rintf(v[k] / s), -127.0f), 127.0f);
        o[k] = f2bf_rn(q);
    }
    ((us4*)qw)[i] = o;
}

// ---------------------------------------------------------------------------
// Shared GEMM machinery: C[M,N] = A[M,K]*B[N,K]^T, 256x256 tile, BK=64,
// 512 thr = 8 waves (2M x 4N). LDS 128KB = 2 buf x {A.k0,A.k1,B.k0,B.k1}
// 16KB regions; chunk swizzle c' = c^((r>>1)&3) (R1: bank conflicts == 0).
// ---------------------------------------------------------------------------
#define AB(b,kh) ((b)*65536 + (kh)*16384)
#define BB(b,kh) ((b)*65536 + 32768 + (kh)*16384)
#define STA(p, eo, rb) gll16(gA[p] + (eo), lds + (rb) + ldst[p])
#define STB(p, eo, rb) gll16(gB[p] + (eo), lds + (rb) + ldst[p])
#define VMC(n) asm volatile("s_waitcnt vmcnt(" #n ")" ::: "memory")

#define PHASE(BUF, KS, MB, STAGE, TAIL) do {                                  \
    bf16x8 aF[4];                                                             \
    _Pragma("unroll")                                                         \
    for (int m_ = 0; m_ < 4; m_++)                                            \
      aF[m_] = *(const bf16x8*)(lds + AB(BUF,KS) + aoff + (MB + m_) * 1024);  \
    if (MB == 0) {                                                            \
      _Pragma("unroll")                                                       \
      for (int n_ = 0; n_ < 4; n_++)                                          \
        bF[n_] = *(const bf16x8*)(lds + BB(BUF,KS) + boff + n_ * 1024);       \
    }                                                                         \
    STAGE                                                                     \
    __builtin_amdgcn_s_barrier();                                             \
    asm volatile("s_waitcnt lgkmcnt(0)" ::: "memory");                        \
    __builtin_amdgcn_s_setprio(1);                                            \
    _Pragma("unroll")                                                         \
    for (int m_ = 0; m_ < 4; m_++)                                            \
      _Pragma("unroll")                                                       \
      for (int n_ = 0; n_ < 4; n_++)                                          \
        acc[MB + m_][n_] = __builtin_amdgcn_mfma_f32_16x16x32_bf16(           \
            aF[m_], bF[n_], acc[MB + m_][n_], 0, 0, 0);                       \
    __builtin_amdgcn_s_setprio(0);                                            \
    TAIL                                                                      \
    __builtin_amdgcn_s_barrier();                                             \
  } while (0)

// ---------------------------------------------------------------------------
// gemm1 (gelu epilogue + h-absmax): R1 pipeline verbatim; epilogue reordered
// n-innermost so each output row's 128B window is written back-to-back
// (R1 counters: 812MB written for 402MB of data = 2x dirty-line churn).
// ---------------------------------------------------------------------------
__global__ __launch_bounds__(512, 2) void gemm256g(
        const unsigned short* __restrict__ A, const unsigned short* __restrict__ B,
        int K, const unsigned* __restrict__ amaxA_bits,
        const unsigned* __restrict__ amaxB_bits, const float* __restrict__ bias,
        unsigned short* __restrict__ Hm, int ldc, unsigned* __restrict__ amax_out) {
    __shared__ __align__(16) char lds[131072];
    __shared__ float red[8];
    int tid = threadIdx.x, lane = tid & 63, wv = tid >> 6;
    int wm = wv >> 2, wn = wv & 3;

    int nwg = gridDim.x * gridDim.y;
    int flat = blockIdx.y * gridDim.x + blockIdx.x;
    int swz = (flat & 7) * (nwg >> 3) + (flat >> 3);
    int ncol = gridDim.x;
    long rowBase = (long)(swz / ncol) * 256;
    long colBase = (long)(swz % ncol) * 256;

    f4 acc[8][4] = {};
    bf16x8 bF[4];

    int rl = lane & 15, cq = lane >> 4;
    int roff = rl * 64 + ((cq ^ ((rl >> 1) & 3)) * 16);
    int aoff = wm * 8192 + roff;
    int boff = wn * 4096 + roff;

    const unsigned short* gA[2]; const unsigned short* gB[2]; int ldst[2];
    #pragma unroll
    for (int p = 0; p < 2; p++) {
        int s = p * 512 + tid;
        int r = s >> 2;
        int gc = (s & 3) ^ ((r >> 1) & 3);
        gA[p] = A + (rowBase + r) * (long)K + gc * 8;
        gB[p] = B + (colBase + r) * (long)K + gc * 8;
        ldst[p] = s * 16;
    }

    // prologue: tile0 fully, then tile1 k0 halves; vmcnt(4) keeps the
    // latter in flight (R1-verified schedule).
    #pragma unroll
    for (int p = 0; p < 2; p++) {
        STA(p, 0,  AB(0,0));
        STA(p, 32, AB(0,1));
        STB(p, 0,  BB(0,0));
        STB(p, 32, BB(0,1));
    }
    #pragma unroll
    for (int p = 0; p < 2; p++) {
        STA(p, 64, AB(1,0));
        STB(p, 64, BB(1,0));
    }
    VMC(4);
    __builtin_amdgcn_s_barrier();

    const int nit = (K >> 7) - 1;
    for (int i = 0; i < nit; i++) {
        PHASE(0,0,0, { STA(0,96,AB(1,1));  STA(1,96,AB(1,1));  }, );
        PHASE(0,0,4, { STB(0,96,BB(1,1));  STB(1,96,BB(1,1));  }, );
        PHASE(0,1,0, { STA(0,128,AB(0,0)); STA(1,128,AB(0,0)); }, );
        PHASE(0,1,4, { STB(0,128,BB(0,0)); STB(1,128,BB(0,0)); }, VMC(4); );
        PHASE(1,0,0, { STA(0,160,AB(0,1)); STA(1,160,AB(0,1)); }, );
        PHASE(1,0,4, { STB(0,160,BB(0,1)); STB(1,160,BB(0,1)); }, );
        PHASE(1,1,0, { STA(0,192,AB(1,0)); STA(1,192,AB(1,0)); }, );
        PHASE(1,1,4, { STB(0,192,BB(1,0)); STB(1,192,BB(1,0)); }, VMC(4); );
        gA[0] += 128; gA[1] += 128; gB[0] += 128; gB[1] += 128;
    }
    PHASE(0,0,0, { STA(0,96,AB(1,1)); STA(1,96,AB(1,1)); }, );
    PHASE(0,0,4, { STB(0,96,BB(1,1)); STB(1,96,BB(1,1)); }, );
    PHASE(0,1,0, { }, );
    PHASE(0,1,4, { }, VMC(0); );
    PHASE(1,0,0, { }, );
    PHASE(1,0,4, { }, );
    PHASE(1,1,0, { }, );
    PHASE(1,1,4, { }, );

    float sA = fmaxf(__uint_as_float(*amaxA_bits) * (1.0f / 128.0f), 1e-12f);
    float sB = fmaxf(__uint_as_float(*amaxB_bits) * (1.0f / 127.0f), 1e-12f);
    float sAB = sA * sB;
    int cr = cq * 4;            // C row base within 16 (row=(lane>>4)*4+reg)
    int cc = rl;                // C col within 16     (col=lane&15)

    float bv[4];
    #pragma unroll
    for (int n = 0; n < 4; n++) bv[n] = bias[colBase + wn * 64 + n * 16 + cc];
    float mx = 0.f;
    #pragma unroll
    for (int m = 0; m < 8; m++) {
        #pragma unroll
        for (int r = 0; r < 4; r++) {
            long ro = (rowBase + wm * 128 + m * 16 + cr + r) * (long)ldc
                      + colBase + wn * 64 + cc;
            #pragma unroll
            for (int n = 0; n < 4; n++) {
                float v = acc[m][n][r] * sAB + bv[n];
                float g = 0.5f * v * (1.0f + erff(v * 0.70710678118654752f));
                mx = fmaxf(mx, fabsf(g));
                Hm[ro + n * 16] = f2bf_rn(g);
            }
        }
    }
    block_atomic_max<8>(mx, amax_out, red, tid);
}

// ---------------------------------------------------------------------------
// gemm2 (fused A-requant, fp32 epilogue): A = raw gelu h (bf16); quantize
// on the fly during staging. Per tile u (4 phases):
//   P0-stage: issue 4x global_load_dwordx4 (A tile u+1, asm-pinned)
//   P1-stage: gll16 B.k0(u+1); P1-tail VMC(6) -> drains B.k1(u) (read @P2)
//   P2-stage: VMC(2) (drains A(u+1)) + sched_barrier + quantize + ds_write
//             A(u+1) into buf^1 (prev contents last read tile u-1, >=3
//             barriers prior); writer's post-barrier lgkmcnt(0) completes
//             the ds_writes before any of its later barriers.
//   P3-stage: gll16 B.k1(u+1); P3-tail VMC(2) -> drains B.k0(u+1) (read
//             @ u+1.P0). Uniform 2-phase latency cover on every load.
// ---------------------------------------------------------------------------
#define QTILE(BUF, NB, AO, BK0, BK1)                                          \
    PHASE(BUF,0,0, { sA0 = gld16(gA[0] + (AO));                               \
                     sA1 = gld16(gA[1] + (AO));                               \
                     sA2 = gld16(gA[0] + (AO) + 32);                          \
                     sA3 = gld16(gA[1] + (AO) + 32); }, );                    \
    PHASE(BUF,0,4, { gll16(gB[0] + (BK0), lds + BB(NB,0) + ldst[0]);          \
                     gll16(gB[1] + (BK0), lds + BB(NB,0) + ldst[1]); },       \
                   VMC(6); );                                                 \
    PHASE(BUF,1,0, { VMC(2); __builtin_amdgcn_sched_barrier(0);               \
                     *(u4*)(lds + AB(NB,0) + ldst[0]) = quant8(sA0, inv_sA);  \
                     *(u4*)(lds + AB(NB,0) + ldst[1]) = quant8(sA1, inv_sA);  \
                     *(u4*)(lds + AB(NB,1) + ldst[0]) = quant8(sA2, inv_sA);  \
                     *(u4*)(lds + AB(NB,1) + ldst[1]) = quant8(sA3, inv_sA); }, ); \
    PHASE(BUF,1,4, { gll16(gB[0] + (BK1), lds + BB(NB,1) + ldst[0]);          \
                     gll16(gB[1] + (BK1), lds + BB(NB,1) + ldst[1]); },       \
                   VMC(2); );

__global__ __launch_bounds__(512, 2) void gemm256q(
        const unsigned short* __restrict__ A, const unsigned short* __restrict__ B,
        int K, const unsigned* __restrict__ amaxA_bits,
        const unsigned* __restrict__ amaxB_bits, const float* __restrict__ bias,
        float* __restrict__ O, int ldc) {
    __shared__ __align__(16) char lds[131072];
    int tid = threadIdx.x, lane = tid & 63, wv = tid >> 6;
    int wm = wv >> 2, wn = wv & 3;

    int nwg = gridDim.x * gridDim.y;
    int flat = blockIdx.y * gridDim.x + blockIdx.x;
    int swz = (flat & 7) * (nwg >> 3) + (flat >> 3);
    int ncol = gridDim.x;
    long rowBase = (long)(swz / ncol) * 256;
    long colBase = (long)(swz % ncol) * 256;

    float sA = fmaxf(__uint_as_float(*amaxA_bits) * (1.0f / 128.0f), 1e-12f);
    float inv_sA = 1.0f / sA;

    f4 acc[8][4] = {};
    bf16x8 bF[4];
    u4 sA0, sA1, sA2, sA3;

    int rl = lane & 15, cq = lane >> 4;
    int roff = rl * 64 + ((cq ^ ((rl >> 1) & 3)) * 16);
    int aoff = wm * 8192 + roff;
    int boff = wn * 4096 + roff;

    const unsigned short* gA[2]; const unsigned short* gB[2]; int ldst[2];
    #pragma unroll
    for (int p = 0; p < 2; p++) {
        int s = p * 512 + tid;
        int r = s >> 2;
        int gc = (s & 3) ^ ((r >> 1) & 3);
        gA[p] = A + (rowBase + r) * (long)K + gc * 8;
        gB[p] = B + (colBase + r) * (long)K + gc * 8;
        ldst[p] = s * 16;
    }

    // prologue: A(0) reg-load + quant + ds_write; B.k0(0) landed; B.k1(0)
    // left in flight (matches steady-state invariant at tile-0 entry).
    sA0 = gld16(gA[0] + 0);  sA1 = gld16(gA[1] + 0);
    sA2 = gld16(gA[0] + 32); sA3 = gld16(gA[1] + 32);
    gll16(gB[0] + 0, lds + BB(0,0) + ldst[0]);
    gll16(gB[1] + 0, lds + BB(0,0) + ldst[1]);
    VMC(2); __builtin_amdgcn_sched_barrier(0);
    *(u4*)(lds + AB(0,0) + ldst[0]) = quant8(sA0, inv_sA);
    *(u4*)(lds + AB(0,0) + ldst[1]) = quant8(sA1, inv_sA);
    *(u4*)(lds + AB(0,1) + ldst[0]) = quant8(sA2, inv_sA);
    *(u4*)(lds + AB(0,1) + ldst[1]) = quant8(sA3, inv_sA);
    gll16(gB[0] + 32, lds + BB(0,1) + ldst[0]);
    gll16(gB[1] + 32, lds + BB(0,1) + ldst[1]);
    VMC(2);                                    // B.k0(0) landed; B.k1 in flight
    asm volatile("s_waitcnt lgkmcnt(0)" ::: "memory");
    __builtin_amdgcn_s_barrier();

    // main loop: tile pairs (2i: buf0 stages->buf1, 2i+1: buf1 stages->buf0)
    const int nit = (K >> 7) - 1;
    for (int i = 0; i < nit; i++) {
        QTILE(0, 1, 64, 64, 96)
        QTILE(1, 0, 128, 128, 160)
        gA[0] += 128; gA[1] += 128; gB[0] += 128; gB[1] += 128;
    }
    // tile NT-2 (buf0): full stage of NT-1
    QTILE(0, 1, 64, 64, 96)
    // tile NT-1 (buf1): bare; drain B.k1(NT-1) before its P2 read
    PHASE(1,0,0, { }, );
    PHASE(1,0,4, { }, VMC(0); );
    PHASE(1,1,0, { }, );
    PHASE(1,1,4, { }, );

    float sB = fmaxf(__uint_as_float(*amaxB_bits) * (1.0f / 127.0f), 1e-12f);
    float sAB = sA * sB;
    int cr = cq * 4;
    int cc = rl;

    float bv[4];
    #pragma unroll
    for (int n = 0; n < 4; n++) bv[n] = bias[colBase + wn * 64 + n * 16 + cc];
    #pragma unroll
    for (int m = 0; m < 8; m++) {
        #pragma unroll
        for (int r = 0; r < 4; r++) {
            long ro = (rowBase + wm * 128 + m * 16 + cr + r) * (long)ldc
                      + colBase + wn * 64 + cc;
            #pragma unroll
            for (int n = 0; n < 4; n++)
                O[ro + n * 16] = acc[m][n][r] * sAB + bv[n];
        }
    }
}

// ---------------------------------------------------------------------------
extern "C" void kernel_launch(void* const* d_in, const int* in_sizes, int n_in,
                              void* d_out, int out_size, void* d_ws, size_t ws_size,
                              hipStream_t stream) {
    const float* x     = (const float*)d_in[0];
    const float* gamma = (const float*)d_in[1];
    const float* beta  = (const float*)d_in[2];
    const float* W1    = (const float*)d_in[3];
    const float* b1    = (const float*)d_in[4];
    const float* W2    = (const float*)d_in[5];
    const float* b2    = (const float*)d_in[6];
    float* out = (float*)d_out;

    const int  D  = in_sizes[1];          // 768
    const int  H  = in_sizes[4];          // 3072
    const long NR = (long)in_sizes[0] / D;  // 65536

    char* ws = (char*)d_ws;
    unsigned* amax = (unsigned*)ws;                 // [0]=x [1]=W1 [2]=W2 [3]=h
    unsigned short* qx  = (unsigned short*)(ws + 256);
    unsigned short* qw1 = qx  + (size_t)NR * D;
    unsigned short* qw2 = qw1 + (size_t)H * D;
    unsigned short* hq  = qw2 + (size_t)H * D;      // NR*H bf16 (raw gelu h)

    hipMemsetAsync(amax, 0, 16, stream);

    long wn4 = (long)H * D / 4;
    absmax_kernel<<<1024, 256, 0, stream>>>(W1, wn4, amax + 1);
    absmax_kernel<<<1024, 256, 0, stream>>>(W2, wn4, amax + 2);
    ln_absmax_kernel<<<2048, 256, 0, stream>>>(x, gamma, beta, amax + 0, NR);

    quant_w_kernel<<<(unsigned)((wn4 + 255) / 256), 256, 0, stream>>>(W1, qw1, wn4, amax + 1);
    quant_w_kernel<<<(unsigned)((wn4 + 255) / 256), 256, 0, stream>>>(W2, qw2, wn4, amax + 2);
    ln_quant_kernel<<<(unsigned)(NR / 4), 256, 0, stream>>>(x, gamma, beta, qx, amax + 0, NR);

    dim3 g1(H / 256, (unsigned)(NR / 256));   // 12 x 256 = 3072 wg (%8==0)
    gemm256g<<<g1, 512, 0, stream>>>(qx, qw1, D, amax + 0, amax + 1, b1,
                                     hq, H, amax + 3);

    // quant_h pass eliminated: gemm256q requantizes A-tiles during staging.
    dim3 g2(D / 256, (unsigned)(NR / 256));   // 3 x 256 = 768 wg (%8==0)
    gemm256q<<<g2, 512, 0, stream>>>(hq, qw2, H, amax + 3, amax + 2, b2,
                                     out, D);
}

// Round 6
// 1169.005 us; speedup vs baseline: 6.7004x; 1.3792x over previous
//
#include <hip/hip_runtime.h>
#include <math.h>

// ---------------------------------------------------------------------------
// QuantMlp: out = fq(h)@fq(W2)^T + b2,  h = gelu(fq(LN(x))@fq(W1)^T + b1)
// fq: per-tensor symmetric int8 fake-quant. q-values are small integers.
//
// R8 (third submission of the int8 design; R6/R7 died at container level with
// no kernel verdict — pod was demonstrably sick: 204MB npz pushes took
// 1175-2564s on the SUCCESSFUL rounds. Kernel-side audit found no fault:
// builtin signature v4i32 x3 matches gfx950 LLVM; all staged addresses exact
// in-bounds and 16B-aligned; barrier/vmcnt schedule is the R1-proven one.)
//
// GEMMs on INT8 MFMA (mfma_i32_16x16x64_i8):
//  - R1 evidence: time ~ phase-count x ~2500cyc (gemm1 48ph x 12 blk/CU ==
//    gemm2 192ph x 3 blk/CU == 604us each). i8 doubles K per instruction and
//    halves staged bytes -> phase count and LDS/L2/L3 traffic both halve.
//  - int32 accumulation is EXACT; identical 16B/lane fragment geometry; the
//    proven R1 8-phase counted-vmcnt schedule is reused with element
//    offsets doubled. A/B share the same lane->k plumbing so any HW k-slot
//    permutation cancels in the dot product.
//  - quant_h is an in-place bf16->int8 pass: each thread reads its own 32B
//    (16 bf16) and overwrites the first 16B with 16 int8 (race-free; gemm1
//    fully rewrites the bf16 image every launch, so replays are safe).
//    gemm2 reads the gapped image via chunk addr gc*32 (GAP=2).
// ---------------------------------------------------------------------------

typedef __attribute__((ext_vector_type(4))) float  f4;
typedef __attribute__((ext_vector_type(4))) int    i32x4;
typedef __attribute__((ext_vector_type(4))) unsigned char  uc4;
typedef __attribute__((ext_vector_type(4))) unsigned int   u4;

__device__ __forceinline__ unsigned short f2bf_rn(float f) {
    unsigned u = __float_as_uint(f);
    u += 0x7FFFu + ((u >> 16) & 1u);          // round-to-nearest-even
    return (unsigned short)(u >> 16);
}

// all-threads block -> single device atomicMax of a non-negative float
template <int NW>
__device__ __forceinline__ void block_atomic_max(float v, unsigned* slot,
                                                 float* red, int tid) {
    int lane = tid & 63, wv = tid >> 6;
    #pragma unroll
    for (int m = 32; m; m >>= 1) v = fmaxf(v, __shfl_xor(v, m));
    if (lane == 0) red[wv] = v;
    __syncthreads();
    if (tid == 0) {
        float r = red[0];
        #pragma unroll
        for (int i = 1; i < NW; i++) r = fmaxf(r, red[i]);
        atomicMax(slot, __float_as_uint(r));
    }
}

// async 16B global->LDS (wave-uniform base + lane*16 by construction)
__device__ __forceinline__ void gll16(const void* g, void* l) {
    __builtin_amdgcn_global_load_lds(
        (const __attribute__((address_space(1))) void*)g,
        (__attribute__((address_space(3))) void*)l, 16, 0, 0);
}

// ---------------------------------------------------------------------------
// LayerNorm helpers: one wave per row of 768 (12 floats/lane as 3x float4)
// ---------------------------------------------------------------------------
__device__ __forceinline__ void ln_row(const f4* xr, int lane, f4 v[3],
                                       float& mu, float& rs) {
    float s = 0.f;
    #pragma unroll
    for (int c = 0; c < 3; c++) {
        v[c] = xr[lane + 64 * c];
        s += v[c][0] + v[c][1] + v[c][2] + v[c][3];
    }
    #pragma unroll
    for (int m = 1; m < 64; m <<= 1) s += __shfl_xor(s, m);
    mu = s * (1.0f / 768.0f);
    float q = 0.f;
    #pragma unroll
    for (int c = 0; c < 3; c++) {
        #pragma unroll
        for (int k = 0; k < 4; k++) { float d = v[c][k] - mu; q += d * d; }
    }
    #pragma unroll
    for (int m = 1; m < 64; m <<= 1) q += __shfl_xor(q, m);
    rs = rsqrtf(q * (1.0f / 768.0f) + 1e-5f);
}

__global__ __launch_bounds__(256) void ln_absmax_kernel(
        const float* __restrict__ x, const float* __restrict__ gamma,
        const float* __restrict__ beta, unsigned* __restrict__ slot, long NR) {
    __shared__ float red[4];
    int tid = threadIdx.x, lane = tid & 63, wv = tid >> 6;
    const f4* g4 = (const f4*)gamma;
    const f4* b4 = (const f4*)beta;
    long rstep = (long)gridDim.x * 4;
    float wmax = 0.f;
    for (long row = (long)blockIdx.x * 4 + wv; row < NR; row += rstep) {
        const f4* xr = (const f4*)(x + row * 768);
        f4 v[3]; float mu, rs;
        ln_row(xr, lane, v, mu, rs);
        #pragma unroll
        for (int c = 0; c < 3; c++) {
            f4 g = g4[lane + 64 * c], b = b4[lane + 64 * c];
            #pragma unroll
            for (int k = 0; k < 4; k++) {
                float xn = (v[c][k] - mu) * rs * g[k] + b[k];
                wmax = fmaxf(wmax, fabsf(xn));
            }
        }
    }
    block_atomic_max<4>(wmax, slot, red, tid);
}

// LN + quantize -> int8 (non-narrow act range)
__global__ __launch_bounds__(256) void ln_quant_kernel(
        const float* __restrict__ x, const float* __restrict__ gamma,
        const float* __restrict__ beta, unsigned char* __restrict__ qx,
        const unsigned* __restrict__ amax_bits, long NR) {
    int tid = threadIdx.x, lane = tid & 63, wv = tid >> 6;
    long row = (long)blockIdx.x * 4 + wv;
    if (row >= NR) return;
    float sx = fmaxf(__uint_as_float(*amax_bits) * (1.0f / 128.0f), 1e-12f);
    const f4* xr = (const f4*)(x + row * 768);
    const f4* g4 = (const f4*)gamma;
    const f4* b4 = (const f4*)beta;
    f4 v[3]; float mu, rs;
    ln_row(xr, lane, v, mu, rs);
    uc4* qr = (uc4*)(qx + row * 768);
    #pragma unroll
    for (int c = 0; c < 3; c++) {
        f4 g = g4[lane + 64 * c], b = b4[lane + 64 * c];
        uc4 o;
        #pragma unroll
        for (int k = 0; k < 4; k++) {
            float xn = (v[c][k] - mu) * rs * g[k] + b[k];
            float q = fminf(fmaxf(rintf(xn / sx), -128.0f), 127.0f);
            o[k] = (unsigned char)(int)q;     // two's complement int8
        }
        qr[lane + 64 * c] = o;
    }
}

// ---------------------------------------------------------------------------
// Weight absmax + quantize (fp32 -> int8, narrow range)
// ---------------------------------------------------------------------------
__global__ __launch_bounds__(256) void absmax_kernel(
        const float* __restrict__ w, long n4, unsigned* __restrict__ slot) {
    __shared__ float red[4];
    int tid = threadIdx.x;
    long stride = (long)gridDim.x * 256;
    float mx = 0.f;
    for (long i = (long)blockIdx.x * 256 + tid; i < n4; i += stride) {
        f4 v = ((const f4*)w)[i];
        mx = fmaxf(mx, fmaxf(fmaxf(fabsf(v[0]), fabsf(v[1])),
                             fmaxf(fabsf(v[2]), fabsf(v[3]))));
    }
    block_atomic_max<4>(mx, slot, red, tid);
}

__global__ __launch_bounds__(256) void quant_w_kernel(
        const float* __restrict__ w, unsigned char* __restrict__ qw, long n4,
        const unsigned* __restrict__ amax_bits) {
    long i = (long)blockIdx.x * 256 + threadIdx.x;
    if (i >= n4) return;
    float s = fmaxf(__uint_as_float(*amax_bits) * (1.0f / 127.0f), 1e-12f);
    f4 v = ((const f4*)w)[i];
    uc4 o;
    #pragma unroll
    for (int k = 0; k < 4; k++) {
        float q = fminf(fmaxf(rintf(v[k] / s), -127.0f), 127.0f);
        o[k] = (unsigned char)(int)q;
    }
    ((uc4*)qw)[i] = o;
}

// h bf16 -> int8, IN PLACE: thread reads its own 32B (16 bf16), writes 16 int8
// into the first 16B of the same region. No inter-thread overlap -> race-free.
// Resulting image: k-chunk c (16 values) at byte 32*c of each row.
__global__ __launch_bounds__(256) void quant_h_kernel(
        unsigned int* __restrict__ h, const unsigned* __restrict__ amax_bits,
        long n32) {
    long i = (long)blockIdx.x * 256 + threadIdx.x;
    if (i >= n32) return;
    float s = fmaxf(__uint_as_float(*amax_bits) * (1.0f / 128.0f), 1e-12f);
    u4 d0 = ((const u4*)h)[2 * i];
    u4 d1 = ((const u4*)h)[2 * i + 1];
    u4 o;
    #pragma unroll
    for (int w = 0; w < 4; w++) {
        unsigned r = 0;
        #pragma unroll
        for (int j = 0; j < 2; j++) {
            unsigned dw = (w < 2) ? d0[(w & 1) * 2 + j] : d1[(w & 1) * 2 + j];
            float lo = __uint_as_float(dw << 16);
            float hi = __uint_as_float(dw & 0xFFFF0000u);
            int qa = (int)fminf(fmaxf(rintf(lo / s), -128.0f), 127.0f);
            int qb = (int)fminf(fmaxf(rintf(hi / s), -128.0f), 127.0f);
            r |= ((unsigned)(unsigned char)qa) << (16 * j);
            r |= ((unsigned)(unsigned char)qb) << (16 * j + 8);
        }
        o[w] = r;
    }
    ((u4*)h)[2 * i] = o;
}

// ---------------------------------------------------------------------------
// GEMM: C[M,N] = A[M,K] * B[N,K]^T, int8 operands, int32 accum (exact).
// 256x256 tile, 512 thr = 8 waves (2M x 4N), per-wave 128x64 out.
// mfma_i32_16x16x64_i8: per lane 16B = 16 consecutive k -> SAME 16B-chunk
// geometry as the bf16 kernel. Region = 256 rows x 64B (K=64 i8), chunk
// swizzle c' = c^((r>>1)&3) (R1-measured: 0 bank conflicts). Tile K=128,
// LDS 128KB = 2 buf x {A.k0,A.k1,B.k0,B.k1} 16KB. Schedule == R1 (proven):
// 8 phases / 2 tiles, vmcnt(4) at ph3/ph7 only, vmcnt(0) only in the tail;
// every region overwrite >=1 barrier after its last read. NT=K/128 even >=4.
// GAP: A-image element stride in bytes (1 = compact int8; 2 = in-place
// requantized h, 16 used + 16 gap per 32B -> chunk addr gc*32).
// ---------------------------------------------------------------------------
#define AB(b,kh) ((b)*65536 + (kh)*16384)
#define BB(b,kh) ((b)*65536 + 32768 + (kh)*16384)
#define STA(p, eo, rb) gll16(gA[p] + (long)(eo) * GAP, lds + (rb) + ldst[p])
#define STB(p, eo, rb) gll16(gB[p] + (eo), lds + (rb) + ldst[p])
#define VMC(n) asm volatile("s_waitcnt vmcnt(" #n ")" ::: "memory")

#define PHASE(BUF, KS, MB, STAGE, TAIL) do {                                  \
    i32x4 aF[4];                                                              \
    _Pragma("unroll")                                                         \
    for (int m_ = 0; m_ < 4; m_++)                                            \
      aF[m_] = *(const i32x4*)(lds + AB(BUF,KS) + aoff + (MB + m_) * 1024);   \
    if (MB == 0) {                                                            \
      _Pragma("unroll")                                                       \
      for (int n_ = 0; n_ < 4; n_++)                                          \
        bF[n_] = *(const i32x4*)(lds + BB(BUF,KS) + boff + n_ * 1024);        \
    }                                                                         \
    STAGE                                                                     \
    __builtin_amdgcn_s_barrier();                                             \
    asm volatile("s_waitcnt lgkmcnt(0)" ::: "memory");                        \
    __builtin_amdgcn_s_setprio(1);                                            \
    _Pragma("unroll")                                                         \
    for (int m_ = 0; m_ < 4; m_++)                                            \
      _Pragma("unroll")                                                       \
      for (int n_ = 0; n_ < 4; n_++)                                          \
        acc[MB + m_][n_] = __builtin_amdgcn_mfma_i32_16x16x64_i8(             \
            aF[m_], bF[n_], acc[MB + m_][n_], 0, 0, 0);                       \
    __builtin_amdgcn_s_setprio(0);                                            \
    TAIL                                                                      \
    __builtin_amdgcn_s_barrier();                                             \
  } while (0)

template <int GAP, int EPI>
__global__ __launch_bounds__(512, 2) void gemm256i(
        const unsigned char* __restrict__ A, const unsigned char* __restrict__ B,
        int K, const unsigned* __restrict__ amaxA_bits,
        const unsigned* __restrict__ amaxB_bits, const float* __restrict__ bias,
        void* __restrict__ Cout, int ldc, unsigned* __restrict__ amax_out) {
    __shared__ __align__(16) char lds[131072];
    __shared__ float red[8];
    int tid = threadIdx.x, lane = tid & 63, wv = tid >> 6;
    int wm = wv >> 2, wn = wv & 3;

    // T1: XCD-contiguous block remap (nwg % 8 == 0 for both launches)
    int nwg = gridDim.x * gridDim.y;
    int flat = blockIdx.y * gridDim.x + blockIdx.x;
    int swz = (flat & 7) * (nwg >> 3) + (flat >> 3);
    int ncol = gridDim.x;
    long rowBase = (long)(swz / ncol) * 256;
    long colBase = (long)(swz % ncol) * 256;

    i32x4 acc[8][4] = {};
    i32x4 bF[4];

    // read-side offsets (bytes; identical to the verified bf16 layout)
    int rl = lane & 15, cq = lane >> 4;
    int roff = rl * 64 + ((cq ^ ((rl >> 1) & 3)) * 16);
    int aoff = wm * 8192 + roff;
    int boff = wn * 4096 + roff;

    // stage-side: slot s -> row r = s>>2, global k-chunk gc (inv swizzle)
    const unsigned char* gA[2]; const unsigned char* gB[2]; int ldst[2];
    #pragma unroll
    for (int p = 0; p < 2; p++) {
        int s = p * 512 + tid;
        int r = s >> 2;
        int gc = (s & 3) ^ ((r >> 1) & 3);
        gA[p] = A + (rowBase + r) * (long)K * GAP + gc * 16 * GAP;
        gB[p] = B + (colBase + r) * (long)K + gc * 16;
        ldst[p] = s * 16;
    }

    // prologue: tile0 fully (k0,k1), then tile1.k0; vmcnt(4) keeps the
    // latter's 4 loads in flight (R1-proven invariant).
    #pragma unroll
    for (int p = 0; p < 2; p++) {
        STA(p, 0,   AB(0,0));
        STA(p, 64,  AB(0,1));
        STB(p, 0,   BB(0,0));
        STB(p, 64,  BB(0,1));
    }
    #pragma unroll
    for (int p = 0; p < 2; p++) {
        STA(p, 128, AB(1,0));
        STB(p, 128, BB(1,0));
    }
    VMC(4);
    __builtin_amdgcn_s_barrier();

    // main loop: tile pairs; eo in i8 k-elements (tile = 128, iter = 256)
    const int nit = (K >> 8) - 1;
    for (int i = 0; i < nit; i++) {
        PHASE(0,0,0, { STA(0,192,AB(1,1)); STA(1,192,AB(1,1)); }, );
        PHASE(0,0,4, { STB(0,192,BB(1,1)); STB(1,192,BB(1,1)); }, );
        PHASE(0,1,0, { STA(0,256,AB(0,0)); STA(1,256,AB(0,0)); }, );
        PHASE(0,1,4, { STB(0,256,BB(0,0)); STB(1,256,BB(0,0)); }, VMC(4); );
        PHASE(1,0,0, { STA(0,320,AB(0,1)); STA(1,320,AB(0,1)); }, );
        PHASE(1,0,4, { STB(0,320,BB(0,1)); STB(1,320,BB(0,1)); }, );
        PHASE(1,1,0, { STA(0,384,AB(1,0)); STA(1,384,AB(1,0)); }, );
        PHASE(1,1,4, { STB(0,384,BB(1,0)); STB(1,384,BB(1,0)); }, VMC(4); );
        gA[0] += 256 * GAP; gA[1] += 256 * GAP; gB[0] += 256; gB[1] += 256;
    }
    // tail tiles NT-2, NT-1: stage last k1, full drain before buf1 reads
    PHASE(0,0,0, { STA(0,192,AB(1,1)); STA(1,192,AB(1,1)); }, );
    PHASE(0,0,4, { STB(0,192,BB(1,1)); STB(1,192,BB(1,1)); }, );
    PHASE(0,1,0, { }, );
    PHASE(0,1,4, { }, VMC(0); );
    PHASE(1,0,0, { }, );
    PHASE(1,0,4, { }, );
    PHASE(1,1,0, { }, );
    PHASE(1,1,4, { }, );

    float sA = fmaxf(__uint_as_float(*amaxA_bits) * (1.0f / 128.0f), 1e-12f);
    float sB = fmaxf(__uint_as_float(*amaxB_bits) * (1.0f / 127.0f), 1e-12f);
    float sAB = sA * sB;
    int cr = cq * 4;            // C row base within 16 (row=(lane>>4)*4+reg)
    int cc = rl;                // C col within 16     (col=lane&15)

    float bv[4];
    #pragma unroll
    for (int n = 0; n < 4; n++) bv[n] = bias[colBase + wn * 64 + n * 16 + cc];

    if (EPI == 0) {
        unsigned short* Hm = (unsigned short*)Cout;
        float mx = 0.f;
        #pragma unroll
        for (int m = 0; m < 8; m++) {
            #pragma unroll
            for (int r = 0; r < 4; r++) {
                long ro = (rowBase + wm * 128 + m * 16 + cr + r) * (long)ldc
                          + colBase + wn * 64 + cc;
                #pragma unroll
                for (int n = 0; n < 4; n++) {
                    float v = (float)acc[m][n][r] * sAB + bv[n];
                    float g = 0.5f * v * (1.0f + erff(v * 0.70710678118654752f));
                    mx = fmaxf(mx, fabsf(g));
                    Hm[ro + n * 16] = f2bf_rn(g);
                }
            }
        }
        block_atomic_max<8>(mx, amax_out, red, tid);
    } else {
        float* O = (float*)Cout;
        #pragma unroll
        for (int m = 0; m < 8; m++) {
            #pragma unroll
            for (int r = 0; r < 4; r++) {
                long ro = (rowBase + wm * 128 + m * 16 + cr + r) * (long)ldc
                          + colBase + wn * 64 + cc;
                #pragma unroll
                for (int n = 0; n < 4; n++)
                    O[ro + n * 16] = (float)acc[m][n][r] * sAB + bv[n];
            }
        }
    }
}

// ---------------------------------------------------------------------------
extern "C" void kernel_launch(void* const* d_in, const int* in_sizes, int n_in,
                              void* d_out, int out_size, void* d_ws, size_t ws_size,
                              hipStream_t stream) {
    const float* x     = (const float*)d_in[0];
    const float* gamma = (const float*)d_in[1];
    const float* beta  = (const float*)d_in[2];
    const float* W1    = (const float*)d_in[3];
    const float* b1    = (const float*)d_in[4];
    const float* W2    = (const float*)d_in[5];
    const float* b2    = (const float*)d_in[6];
    float* out = (float*)d_out;

    const int  D  = in_sizes[1];          // 768
    const int  H  = in_sizes[4];          // 3072
    const long NR = (long)in_sizes[0] / D;  // 65536

    char* ws = (char*)d_ws;
    unsigned* amax = (unsigned*)ws;                 // [0]=x [1]=W1 [2]=W2 [3]=h
    unsigned char* qx  = (unsigned char*)(ws + 256);        // NR*D int8
    unsigned char* qw1 = qx  + (size_t)NR * D;              // H*D int8
    unsigned char* qw2 = qw1 + (size_t)H * D;               // D*H int8
    unsigned short* hq = (unsigned short*)(qw2 + (size_t)H * D); // NR*H bf16

    hipMemsetAsync(amax, 0, 16, stream);

    long wn4 = (long)H * D / 4;
    absmax_kernel<<<1024, 256, 0, stream>>>(W1, wn4, amax + 1);
    absmax_kernel<<<1024, 256, 0, stream>>>(W2, wn4, amax + 2);
    ln_absmax_kernel<<<2048, 256, 0, stream>>>(x, gamma, beta, amax + 0, NR);

    quant_w_kernel<<<(unsigned)((wn4 + 255) / 256), 256, 0, stream>>>(W1, qw1, wn4, amax + 1);
    quant_w_kernel<<<(unsigned)((wn4 + 255) / 256), 256, 0, stream>>>(W2, qw2, wn4, amax + 2);
    ln_quant_kernel<<<(unsigned)(NR / 4), 256, 0, stream>>>(x, gamma, beta, qx, amax + 0, NR);

    dim3 g1(H / 256, (unsigned)(NR / 256));   // 12 x 256 = 3072 wg (%8==0)
    gemm256i<1, 0><<<g1, 512, 0, stream>>>(qx, qw1, D, amax + 0, amax + 1, b1,
                                           (void*)hq, H, amax + 3);

    long n32 = NR * (long)H / 16;             // 32B regions of h
    quant_h_kernel<<<(unsigned)((n32 + 255) / 256), 256, 0, stream>>>(
        (unsigned int*)hq, amax + 3, n32);

    dim3 g2(D / 256, (unsigned)(NR / 256));   // 3 x 256 = 768 wg (%8==0)
    gemm256i<2, 1><<<g2, 512, 0, stream>>>((const unsigned char*)hq, qw2, H,
                                           amax + 3, amax + 2, b2,
                                           (void*)out, D, nullptr);
}